// Round 3
// baseline (715.627 us; speedup 1.0000x reference)
//
#include <hip/hip_runtime.h>
#include <hip/hip_bf16.h>
#include <stdint.h>

#define T_DIM 2048
#define B_DIM 4
#define E_DIM 1024
#define H_DIM 16
#define EHD 64
#define L2E 1.4426950408889634f
// folded into Q projection epilogue: score_scale * log2(e)
#define QSCALE (0.125f * L2E)

typedef __attribute__((ext_vector_type(8))) short bf16x8;
typedef __attribute__((ext_vector_type(4))) float f32x4;

__device__ __forceinline__ unsigned short f2bf(float x) {
  unsigned int u = __builtin_bit_cast(unsigned int, x);
  u += 0x7fffu + ((u >> 16) & 1u);
  return (unsigned short)(u >> 16);
}

__device__ __forceinline__ void gload16(const void* g, void* l) {
  __builtin_amdgcn_global_load_lds(
      (const __attribute__((address_space(1))) void*)g,
      (__attribute__((address_space(3))) void*)l, 16, 0, 0);
}

// ---------------- fp32 -> bf16 ----------------
__global__ __launch_bounds__(256) void cvt_kernel(const float4* __restrict__ in,
                                                  uint2* __restrict__ out, int n4) {
  int i = blockIdx.x * 256 + threadIdx.x;
  int stride = gridDim.x * 256;
  for (; i < n4; i += stride) {
    float4 f = in[i];
    uint2 o;
    o.x = (unsigned)f2bf(f.x) | ((unsigned)f2bf(f.y) << 16);
    o.y = (unsigned)f2bf(f.z) | ((unsigned)f2bf(f.w) << 16);
    out[i] = o;
  }
}

// ---------------- 128x128 bf16 NT GEMM (m97 structure) ----------------
// MODE 0: QKV projection -> scatter bf16 into QKV[which][b][h][t][d];
//         Q third is pre-scaled by 0.125*log2(e) (folded attention scale).
// MODE 1: out projection -> FP32 out[(t*B+b)*E + n].
template <int MODE>
__global__ __launch_bounds__(256) void gemm_kernel(
    const unsigned short* __restrict__ Abase,
    const unsigned short* __restrict__ Bt,
    const float* __restrict__ bias,
    void* __restrict__ outv, int K) {
  __shared__ alignas(16) short As[128 * 32];
  __shared__ alignas(16) short Bs[128 * 32];
  const int tid = threadIdx.x;
  const int lane = tid & 63, wave = tid >> 6;
  const int m0 = blockIdx.x * 128, n0 = blockIdx.y * 128;
  const int wr = wave >> 1, wc = wave & 1;
  const int lrow = lane & 15, lgrp = lane >> 4;

  const unsigned short* A = Abase;
  if (MODE == 0) A += (size_t)(n0 >> 10) * (8192u * 1024u);

  f32x4 acc[4][4];
#pragma unroll
  for (int m = 0; m < 4; ++m)
#pragma unroll
    for (int n = 0; n < 4; ++n) acc[m][n] = (f32x4){0.f, 0.f, 0.f, 0.f};

  const int srow = wave * 16 + (lane >> 2);
  const int scol = (lane & 3) * 8;
  short* lA0 = As + wave * 16 * 32;
  short* lA1 = As + (64 + wave * 16) * 32;
  short* lB0 = Bs + wave * 16 * 32;
  short* lB1 = Bs + (64 + wave * 16) * 32;

  for (int k0 = 0; k0 < K; k0 += 32) {
    const unsigned short* ga = A + (size_t)(m0 + srow) * K + k0 + scol;
    const unsigned short* gb = Bt + (size_t)(n0 + srow) * K + k0 + scol;
    gload16(ga, lA0);
    gload16(ga + (size_t)64 * K, lA1);
    gload16(gb, lB0);
    gload16(gb + (size_t)64 * K, lB1);
    __syncthreads();
    const short* pa = As + (wr * 64 + lrow) * 32 + lgrp * 8;
    const short* pb = Bs + (wc * 64 + lrow) * 32 + lgrp * 8;
    bf16x8 a[4], b[4];
#pragma unroll
    for (int m = 0; m < 4; ++m) a[m] = *(const bf16x8*)(pa + m * 512);
#pragma unroll
    for (int n = 0; n < 4; ++n) b[n] = *(const bf16x8*)(pb + n * 512);
#pragma unroll
    for (int m = 0; m < 4; ++m)
#pragma unroll
      for (int n = 0; n < 4; ++n)
        acc[m][n] = __builtin_amdgcn_mfma_f32_16x16x32_bf16(a[m], b[n], acc[m][n], 0, 0, 0);
    __syncthreads();
  }

#pragma unroll
  for (int n = 0; n < 4; ++n) {
    const int gn = n0 + wc * 64 + n * 16 + lrow;
    const float bv = bias[gn];
    if (MODE == 0) {
      unsigned short* out = (unsigned short*)outv;
      const int which = gn >> 10;
      const float qsc = (which == 0) ? QSCALE : 1.0f;
      const int e = gn & 1023;
      const int hh = e >> 6, dd = e & 63;
      unsigned short* op =
          out + ((size_t)which * B_DIM * H_DIM + hh) * (size_t)(T_DIM * EHD) + dd;
#pragma unroll
      for (int m = 0; m < 4; ++m)
#pragma unroll
        for (int r = 0; r < 4; ++r) {
          const int gm = m0 + wr * 64 + m * 16 + lgrp * 4 + r;
          const int t = gm >> 2, bb = gm & 3;  // row index is t*B + b
          op[(size_t)bb * H_DIM * (T_DIM * EHD) + (size_t)t * EHD] =
              f2bf((acc[m][n][r] + bv) * qsc);
        }
    } else {
      float* out = (float*)outv;
#pragma unroll
      for (int m = 0; m < 4; ++m)
#pragma unroll
        for (int r = 0; r < 4; ++r) {
          const int gm = m0 + wr * 64 + m * 16 + lgrp * 4 + r;  // row = b*T + t
          const int bb = gm >> 11, t = gm & 2047;
          out[((size_t)t * B_DIM + bb) * E_DIM + gn] = acc[m][n][r] + bv;
        }
    }
  }
}

// ---------------- V transpose: [bh][t][d] -> tile-blocked [bh][t/64][d][64] ----
__global__ __launch_bounds__(256) void transpose_v(const unsigned short* __restrict__ V,
                                                   unsigned short* __restrict__ Vt) {
  __shared__ unsigned short tile[64][68];
  const int bh = blockIdx.y, t0 = blockIdx.x * 64, tid = threadIdx.x;
  const size_t ib = (size_t)bh * (T_DIM * EHD);
  for (int i = tid; i < 1024; i += 256) {
    const int r = i >> 4, c = (i & 15) * 4;
    *(uint2*)&tile[r][c] = *(const uint2*)(V + ib + (size_t)(t0 + r) * EHD + c);
  }
  __syncthreads();
  for (int i = tid; i < 1024; i += 256) {
    const int d = i >> 4, c = (i & 15) * 4;
    uint2 o;
    o.x = (unsigned)tile[c + 0][d] | ((unsigned)tile[c + 1][d] << 16);
    o.y = (unsigned)tile[c + 2][d] | ((unsigned)tile[c + 3][d] << 16);
    // tile-blocked: [bh][tile=t0/64][d][tloc]  (tile stride = 64*64 = t0*EHD)
    *(uint2*)(Vt + ib + (size_t)t0 * EHD + d * 64 + c) = o;
  }
}

// ---------------- flash attention, swapped operands, no K/V staging ----------
// grid (T/64, B*H), 4 waves x 16 q. Lane owns q = lane&15; softmax fully
// in-lane except two shfl_xor. K and tiled-V^T fragments read direct from
// global (L2-resident). Only P goes through per-wave LDS (pad 80: uniform).
__global__ __launch_bounds__(256) void attn_kernel(
    const unsigned short* __restrict__ Qm, const unsigned short* __restrict__ Km,
    const unsigned short* __restrict__ Vtm, const float* __restrict__ mask,
    unsigned short* __restrict__ ctx) {
  __shared__ alignas(16) short Pl[4][16 * 80];
  const int tid = threadIdx.x, lane = tid & 63, wave = tid >> 6;
  const int lrow = lane & 15, lgrp = lane >> 4;
  const int bh = blockIdx.y;
  const int b = bh >> 4, h = bh & 15;
  const int q0 = blockIdx.x * 64;
  const int q = q0 + wave * 16 + lrow;  // this lane's q row

  const size_t base = (size_t)bh * (T_DIM * EHD);
  // Q as B-operand (col = q = lrow), pre-scaled by 0.125*log2e in GEMM epilogue
  const unsigned short* qp = Qm + base + (size_t)q * EHD + lgrp * 8;
  const bf16x8 qf0 = *(const bf16x8*)qp;
  const bf16x8 qf1 = *(const bf16x8*)(qp + 32);

  // K fragment base: row k = lrow (+n*16), d-chunk lgrp*8; advances 64 rows/iter
  const unsigned short* kp = Km + base + (size_t)lrow * EHD + lgrp * 8;
  // tiled V^T fragment base: row d = lrow (+n*16), k-chunk; 4096 shorts per tile
  const unsigned short* vp = Vtm + base + (size_t)lrow * 64 + lgrp * 8;
  // mask: this lane's q row, k = kv0 + n*16 + lgrp*4 + r  -> float4
  const float* mp = mask + (size_t)q * T_DIM + lgrp * 4;

  f32x4 oacc[4];  // oacc[n][r]: d = n*16 + lgrp*4 + r, q = lrow
#pragma unroll
  for (int n = 0; n < 4; ++n) oacc[n] = (f32x4){0.f, 0.f, 0.f, 0.f};
  float mrun = -1e30f, lrun = 0.f;
  short* pl = Pl[wave];
  short* plw = pl + lrow * 80 + lgrp * 4;
  const short* plr = pl + lrow * 80 + lgrp * 8;

  for (int it = 0; it < 32; ++it) {
    float sv[4][4];
#pragma unroll
    for (int n = 0; n < 4; ++n) {
      const bf16x8 kf0 = *(const bf16x8*)(kp + n * 1024);
      const bf16x8 kf1 = *(const bf16x8*)(kp + n * 1024 + 32);
      f32x4 s = (f32x4){0.f, 0.f, 0.f, 0.f};
      s = __builtin_amdgcn_mfma_f32_16x16x32_bf16(kf0, qf0, s, 0, 0, 0);
      s = __builtin_amdgcn_mfma_f32_16x16x32_bf16(kf1, qf1, s, 0, 0, 0);
      const float4 mq = *(const float4*)(mp + n * 16);
      sv[n][0] = s[0] * mq.x;
      sv[n][1] = s[1] * mq.y;
      sv[n][2] = s[2] * mq.z;
      sv[n][3] = s[3] * mq.w;
    }

    // row max over this tile (in-lane 15 + 2 shuffles over lgrp)
    float pmax = sv[0][0];
#pragma unroll
    for (int n = 0; n < 4; ++n)
#pragma unroll
      for (int r = 0; r < 4; ++r) pmax = fmaxf(pmax, sv[n][r]);
    pmax = fmaxf(pmax, __shfl_xor(pmax, 16));
    pmax = fmaxf(pmax, __shfl_xor(pmax, 32));

    // defer-max: rescale only when tile max exceeds running max by >8 (nats)
    if (!__all(pmax - mrun <= 11.5f)) {
      const float mn = fmaxf(mrun, pmax);
      const float corr = __builtin_amdgcn_exp2f(mrun - mn);
      mrun = mn;
      lrun *= corr;
#pragma unroll
      for (int n = 0; n < 4; ++n)
#pragma unroll
        for (int r = 0; r < 4; ++r) oacc[n][r] *= corr;
    }

    float rsum = 0.f;
#pragma unroll
    for (int n = 0; n < 4; ++n) {
      const float p0 = __builtin_amdgcn_exp2f(sv[n][0] - mrun);
      const float p1 = __builtin_amdgcn_exp2f(sv[n][1] - mrun);
      const float p2 = __builtin_amdgcn_exp2f(sv[n][2] - mrun);
      const float p3 = __builtin_amdgcn_exp2f(sv[n][3] - mrun);
      rsum += (p0 + p1) + (p2 + p3);
      uint2 w;
      w.x = (unsigned)f2bf(p0) | ((unsigned)f2bf(p1) << 16);
      w.y = (unsigned)f2bf(p2) | ((unsigned)f2bf(p3) << 16);
      *(uint2*)(plw + n * 16) = w;  // P[q=lrow][k=n*16+lgrp*4 ..+3]
    }
    rsum += __shfl_xor(rsum, 16);
    rsum += __shfl_xor(rsum, 32);
    lrun += rsum;

#pragma unroll
    for (int kc = 0; kc < 2; ++kc) {
      const bf16x8 pB = *(const bf16x8*)(plr + kc * 32);  // P[k chunk][q=lrow]
#pragma unroll
      for (int n = 0; n < 4; ++n) {
        const bf16x8 vf = *(const bf16x8*)(vp + n * 1024 + kc * 32);
        oacc[n] = __builtin_amdgcn_mfma_f32_16x16x32_bf16(vf, pB, oacc[n], 0, 0, 0);
      }
    }
    kp += 4096;
    vp += 4096;
    mp += 64;
  }

  const float inv = 1.f / lrun;
  unsigned short* cp = ctx + ((size_t)b * T_DIM + q) * E_DIM + h * EHD + lgrp * 4;
#pragma unroll
  for (int n = 0; n < 4; ++n) {
    uint2 w;
    w.x = (unsigned)f2bf(oacc[n][0] * inv) | ((unsigned)f2bf(oacc[n][1] * inv) << 16);
    w.y = (unsigned)f2bf(oacc[n][2] * inv) | ((unsigned)f2bf(oacc[n][3] * inv) << 16);
    *(uint2*)(cp + n * 16) = w;
  }
}

extern "C" void kernel_launch(void* const* d_in, const int* in_sizes, int n_in,
                              void* d_out, int out_size, void* d_ws, size_t ws_size,
                              hipStream_t stream) {
  const float* q    = (const float*)d_in[0];
  const float* k    = (const float*)d_in[1];
  const float* v    = (const float*)d_in[2];
  const float* mask = (const float*)d_in[3];
  const float* wqkv = (const float*)d_in[4];
  const float* bqkv = (const float*)d_in[5];
  const float* wout = (const float*)d_in[6];
  const float* bout = (const float*)d_in[7];

  char* ws = (char*)d_ws;
  unsigned short* Xb   = (unsigned short*)(ws);
  unsigned short* Wqb  = (unsigned short*)(ws + 50331648);
  unsigned short* Wob  = (unsigned short*)(ws + 56623104);
  unsigned short* QKVb = (unsigned short*)(ws + 58720256);
  unsigned short* CTXb = (unsigned short*)(ws);             // [B][T][E]
  unsigned short* Vtb  = (unsigned short*)(ws + 16777216);  // [bh][t/64][d][64]

  cvt_kernel<<<2048, 256, 0, stream>>>((const float4*)q, (uint2*)Xb, 2097152);
  cvt_kernel<<<2048, 256, 0, stream>>>((const float4*)k, (uint2*)(Xb + 8388608), 2097152);
  cvt_kernel<<<2048, 256, 0, stream>>>((const float4*)v, (uint2*)(Xb + 16777216), 2097152);
  cvt_kernel<<<1024, 256, 0, stream>>>((const float4*)wqkv, (uint2*)Wqb, 786432);
  cvt_kernel<<<512, 256, 0, stream>>>((const float4*)wout, (uint2*)Wob, 262144);

  gemm_kernel<0><<<dim3(64, 24), 256, 0, stream>>>(Xb, Wqb, bqkv, QKVb, 1024);
  transpose_v<<<dim3(32, 64), 256, 0, stream>>>(QKVb + 16777216, Vtb);
  attn_kernel<<<dim3(32, 64), 256, 0, stream>>>(QKVb, QKVb + 8388608, Vtb, mask, CTXb);
  gemm_kernel<1><<<dim3(64, 8), 256, 0, stream>>>(CTXb, Wob, bout, d_out, 1024);
}

// Round 4
// 348.765 us; speedup vs baseline: 2.0519x; 2.0519x over previous
//
#include <hip/hip_runtime.h>
#include <hip/hip_bf16.h>
#include <stdint.h>

#define T_DIM 2048
#define B_DIM 4
#define E_DIM 1024
#define H_DIM 16
#define EHD 64
#define L2E 1.4426950408889634f
// folded into Q projection epilogue: score_scale * log2(e)
#define QSCALE (0.125f * L2E)

typedef __attribute__((ext_vector_type(8))) short bf16x8;
typedef __attribute__((ext_vector_type(4))) float f32x4;

__device__ __forceinline__ unsigned short f2bf(float x) {
  unsigned int u = __builtin_bit_cast(unsigned int, x);
  u += 0x7fffu + ((u >> 16) & 1u);
  return (unsigned short)(u >> 16);
}

__device__ __forceinline__ void gload16(const void* g, void* l) {
  __builtin_amdgcn_global_load_lds(
      (const __attribute__((address_space(1))) void*)g,
      (__attribute__((address_space(3))) void*)l, 16, 0, 0);
}

// ---------------- fp32 -> bf16 ----------------
__global__ __launch_bounds__(256) void cvt_kernel(const float4* __restrict__ in,
                                                  uint2* __restrict__ out, int n4) {
  int i = blockIdx.x * 256 + threadIdx.x;
  int stride = gridDim.x * 256;
  for (; i < n4; i += stride) {
    float4 f = in[i];
    uint2 o;
    o.x = (unsigned)f2bf(f.x) | ((unsigned)f2bf(f.y) << 16);
    o.y = (unsigned)f2bf(f.z) | ((unsigned)f2bf(f.w) << 16);
    out[i] = o;
  }
}

// ---------------- 128x128 bf16 NT GEMM (m97 structure) ----------------
// MODE 0: QKV projection. Q third pre-scaled by 0.125*log2e; Q,K scattered to
//         [b][h][t][d]; V scattered DIRECTLY to tiled-transposed
//         Vt[bh][t/64][d][t%64] (replaces separate transpose kernel).
// MODE 1: out projection -> FP32 out[(t*B+b)*E + n].
template <int MODE>
__global__ __launch_bounds__(256) void gemm_kernel(
    const unsigned short* __restrict__ Abase,
    const unsigned short* __restrict__ Bt,
    const float* __restrict__ bias,
    void* __restrict__ outv, int K) {
  __shared__ alignas(16) short As[128 * 32];
  __shared__ alignas(16) short Bs[128 * 32];
  const int tid = threadIdx.x;
  const int lane = tid & 63, wave = tid >> 6;
  const int m0 = blockIdx.x * 128, n0 = blockIdx.y * 128;
  const int wr = wave >> 1, wc = wave & 1;
  const int lrow = lane & 15, lgrp = lane >> 4;

  const unsigned short* A = Abase;
  if (MODE == 0) A += (size_t)(n0 >> 10) * (8192u * 1024u);

  f32x4 acc[4][4];
#pragma unroll
  for (int m = 0; m < 4; ++m)
#pragma unroll
    for (int n = 0; n < 4; ++n) acc[m][n] = (f32x4){0.f, 0.f, 0.f, 0.f};

  const int srow = wave * 16 + (lane >> 2);
  const int scol = (lane & 3) * 8;
  short* lA0 = As + wave * 16 * 32;
  short* lA1 = As + (64 + wave * 16) * 32;
  short* lB0 = Bs + wave * 16 * 32;
  short* lB1 = Bs + (64 + wave * 16) * 32;

  for (int k0 = 0; k0 < K; k0 += 32) {
    const unsigned short* ga = A + (size_t)(m0 + srow) * K + k0 + scol;
    const unsigned short* gb = Bt + (size_t)(n0 + srow) * K + k0 + scol;
    gload16(ga, lA0);
    gload16(ga + (size_t)64 * K, lA1);
    gload16(gb, lB0);
    gload16(gb + (size_t)64 * K, lB1);
    __syncthreads();
    const short* pa = As + (wr * 64 + lrow) * 32 + lgrp * 8;
    const short* pb = Bs + (wc * 64 + lrow) * 32 + lgrp * 8;
    bf16x8 a[4], b[4];
#pragma unroll
    for (int m = 0; m < 4; ++m) a[m] = *(const bf16x8*)(pa + m * 512);
#pragma unroll
    for (int n = 0; n < 4; ++n) b[n] = *(const bf16x8*)(pb + n * 512);
#pragma unroll
    for (int m = 0; m < 4; ++m)
#pragma unroll
      for (int n = 0; n < 4; ++n)
        acc[m][n] = __builtin_amdgcn_mfma_f32_16x16x32_bf16(a[m], b[n], acc[m][n], 0, 0, 0);
    __syncthreads();
  }

#pragma unroll
  for (int n = 0; n < 4; ++n) {
    const int gn = n0 + wc * 64 + n * 16 + lrow;
    const float bv = bias[gn];
    if (MODE == 0) {
      unsigned short* out = (unsigned short*)outv;
      const int which = gn >> 10;
      const float qsc = (which == 0) ? QSCALE : 1.0f;
      const int e = gn & 1023;
      const int hh = e >> 6, dd = e & 63;
#pragma unroll
      for (int m = 0; m < 4; ++m)
#pragma unroll
        for (int r = 0; r < 4; ++r) {
          const int gm = m0 + wr * 64 + m * 16 + lgrp * 4 + r;
          const int t = gm >> 2, bb = gm & 3;  // A row index is t*B + b
          const unsigned short val = f2bf((acc[m][n][r] + bv) * qsc);
          if (which == 2) {
            // Vt[bh][t>>6][dd][t&63], bh = bb*16+hh
            out[((size_t)(2 * B_DIM * H_DIM) + bb * H_DIM + hh) * (T_DIM * EHD) +
                (size_t)(t >> 6) * 4096 + dd * 64 + (t & 63)] = val;
          } else {
            out[((size_t)which * B_DIM * H_DIM + bb * H_DIM + hh) * (T_DIM * EHD) +
                (size_t)t * EHD + dd] = val;
          }
        }
    } else {
      float* out = (float*)outv;
#pragma unroll
      for (int m = 0; m < 4; ++m)
#pragma unroll
        for (int r = 0; r < 4; ++r) {
          const int gm = m0 + wr * 64 + m * 16 + lgrp * 4 + r;  // row = b*T + t
          const int bb = gm >> 11, t = gm & 2047;
          out[((size_t)t * B_DIM + bb) * E_DIM + gn] = acc[m][n][r] + bv;
        }
    }
  }
}

// ---------------- flash attention: swapped operands + staged K/V ------------
// grid (T/128, B*H), 4 waves. Each wave owns 2 q-groups of 16 rows (q=lrow).
// K/V double-buffered in XOR-swizzled LDS via global_load_lds (2-phase
// pipeline: prefetch next tile before computing current; one barrier/tile).
// Softmax fully in-lane (+2 shfl); P via XOR-swizzled per-wave LDS.
__global__ __launch_bounds__(256, 3) void attn_kernel(
    const unsigned short* __restrict__ Qm, const unsigned short* __restrict__ Km,
    const unsigned short* __restrict__ Vtm, const float* __restrict__ mask,
    unsigned short* __restrict__ ctx) {
  __shared__ alignas(16) short Ks[2][4096];
  __shared__ alignas(16) short Vs[2][4096];
  __shared__ alignas(16) short Pl[4][2][1024];
  const int tid = threadIdx.x, lane = tid & 63, wave = tid >> 6;
  const int lrow = lane & 15, lgrp = lane >> 4;
  const int bh = blockIdx.y, b = bh >> 4, h = bh & 15;
  const int q0 = blockIdx.x * 128;

  const size_t base = (size_t)bh * (T_DIM * EHD);

  // Q fragments for both q-groups (Q pre-scaled by 0.125*log2e in GEMM)
  bf16x8 qf0[2], qf1[2];
  int qrow[2];
  const float* mp[2];
#pragma unroll
  for (int g = 0; g < 2; ++g) {
    qrow[g] = q0 + g * 64 + wave * 16 + lrow;
    const unsigned short* qp = Qm + base + (size_t)qrow[g] * EHD + lgrp * 8;
    qf0[g] = *(const bf16x8*)qp;
    qf1[g] = *(const bf16x8*)(qp + 32);
    mp[g] = mask + (size_t)qrow[g] * T_DIM + lgrp * 4;
  }

  f32x4 oacc[2][4];
#pragma unroll
  for (int g = 0; g < 2; ++g)
#pragma unroll
    for (int n = 0; n < 4; ++n) oacc[g][n] = (f32x4){0.f, 0.f, 0.f, 0.f};
  float mrun[2] = {-1e30f, -1e30f}, lrun[2] = {0.f, 0.f};

  // staging: row-sub rr = lane>>3, source col pre-swizzled so linear LDS dest
  // holds LDS[row][col ^ ((row&7)*8)]  (both-sides involution, G21)
  const int rr = lane >> 3;
  const int cs = (((lane & 7) ^ rr) * 8);
  const int r0w = wave * 8;
  // fragment-read swizzle key
  const int rx = (lrow & 7) * 8;
  const int c0 = (lgrp * 8) ^ rx;  // kc=0 col; kc=1 is c0^32

#define STAGE(bufi, kv0)                                                        \
  {                                                                             \
    _Pragma("unroll") for (int i = 0; i < 2; ++i) {                             \
      const int r0 = i * 32 + r0w;                                              \
      gload16(Km + base + (size_t)((kv0) + r0 + rr) * EHD + cs,                 \
              &Ks[bufi][r0 * 64]);                                              \
      gload16(Vtm + base + (size_t)(kv0) * EHD + (r0 + rr) * 64 + cs,           \
              &Vs[bufi][r0 * 64]);                                              \
    }                                                                           \
  }

  STAGE(0, 0);
  __syncthreads();

  for (int it = 0; it < 32; ++it) {
    const int buf = it & 1;
    if (it < 31) STAGE(buf ^ 1, (it + 1) * 64);  // prefetch overlaps compute

    const short* kb = Ks[buf];
    const short* vb = Vs[buf];

    // ---- QK^T (swapped: C[k][q], q = lrow), K fragments shared by groups ----
    float sv[2][4][4];
#pragma unroll
    for (int n = 0; n < 4; ++n) {
      const short* kp = kb + (n * 16 + lrow) * 64;
      const bf16x8 kf0 = *(const bf16x8*)(kp + c0);
      const bf16x8 kf1 = *(const bf16x8*)(kp + (c0 ^ 32));
      f32x4 s0 = (f32x4){0.f, 0.f, 0.f, 0.f}, s1 = s0;
      s0 = __builtin_amdgcn_mfma_f32_16x16x32_bf16(kf0, qf0[0], s0, 0, 0, 0);
      s0 = __builtin_amdgcn_mfma_f32_16x16x32_bf16(kf1, qf1[0], s0, 0, 0, 0);
      s1 = __builtin_amdgcn_mfma_f32_16x16x32_bf16(kf0, qf0[1], s1, 0, 0, 0);
      s1 = __builtin_amdgcn_mfma_f32_16x16x32_bf16(kf1, qf1[1], s1, 0, 0, 0);
      const float4 m0 = *(const float4*)(mp[0] + n * 16);
      const float4 m1 = *(const float4*)(mp[1] + n * 16);
      sv[0][n][0] = s0[0] * m0.x; sv[0][n][1] = s0[1] * m0.y;
      sv[0][n][2] = s0[2] * m0.z; sv[0][n][3] = s0[3] * m0.w;
      sv[1][n][0] = s1[0] * m1.x; sv[1][n][1] = s1[1] * m1.y;
      sv[1][n][2] = s1[2] * m1.z; sv[1][n][3] = s1[3] * m1.w;
    }

    // ---- softmax per group (in-lane + 2 shfl), P -> swizzled LDS ----
#pragma unroll
    for (int g = 0; g < 2; ++g) {
      float pmax = sv[g][0][0];
#pragma unroll
      for (int n = 0; n < 4; ++n)
#pragma unroll
        for (int r = 0; r < 4; ++r) pmax = fmaxf(pmax, sv[g][n][r]);
      pmax = fmaxf(pmax, __shfl_xor(pmax, 16));
      pmax = fmaxf(pmax, __shfl_xor(pmax, 32));

      if (!__all(pmax - mrun[g] <= 11.5f)) {  // defer-max (T13)
        const float mn = fmaxf(mrun[g], pmax);
        const float corr = __builtin_amdgcn_exp2f(mrun[g] - mn);
        mrun[g] = mn;
        lrun[g] *= corr;
#pragma unroll
        for (int n = 0; n < 4; ++n)
#pragma unroll
          for (int r = 0; r < 4; ++r) oacc[g][n][r] *= corr;
      }

      float rsum = 0.f;
      short* plw = &Pl[wave][g][lrow * 64];
#pragma unroll
      for (int n = 0; n < 4; ++n) {
        const float p0 = __builtin_amdgcn_exp2f(sv[g][n][0] - mrun[g]);
        const float p1 = __builtin_amdgcn_exp2f(sv[g][n][1] - mrun[g]);
        const float p2 = __builtin_amdgcn_exp2f(sv[g][n][2] - mrun[g]);
        const float p3 = __builtin_amdgcn_exp2f(sv[g][n][3] - mrun[g]);
        rsum += (p0 + p1) + (p2 + p3);
        uint2 w;
        w.x = (unsigned)f2bf(p0) | ((unsigned)f2bf(p1) << 16);
        w.y = (unsigned)f2bf(p2) | ((unsigned)f2bf(p3) << 16);
        *(uint2*)(plw + ((n * 16 + lgrp * 4) ^ rx)) = w;
      }
      rsum += __shfl_xor(rsum, 16);
      rsum += __shfl_xor(rsum, 32);
      lrun[g] += rsum;
    }

    // ---- PV (swapped: O[d][q]); V fragments shared by both groups ----
#pragma unroll
    for (int kc = 0; kc < 2; ++kc) {
      const int pc = ((kc * 32) + lgrp * 8) ^ rx;
      const bf16x8 pB0 = *(const bf16x8*)(&Pl[wave][0][lrow * 64] + pc);
      const bf16x8 pB1 = *(const bf16x8*)(&Pl[wave][1][lrow * 64] + pc);
#pragma unroll
      for (int n = 0; n < 4; ++n) {
        const bf16x8 vf = *(const bf16x8*)(vb + (n * 16 + lrow) * 64 + pc);
        oacc[0][n] = __builtin_amdgcn_mfma_f32_16x16x32_bf16(vf, pB0, oacc[0][n], 0, 0, 0);
        oacc[1][n] = __builtin_amdgcn_mfma_f32_16x16x32_bf16(vf, pB1, oacc[1][n], 0, 0, 0);
      }
    }
    mp[0] += 64;
    mp[1] += 64;
    __syncthreads();  // drains prefetch (vmcnt 0) + protects buffer swap
  }

#pragma unroll
  for (int g = 0; g < 2; ++g) {
    const float inv = 1.f / lrun[g];
    unsigned short* cp =
        ctx + ((size_t)b * T_DIM + qrow[g]) * E_DIM + h * EHD + lgrp * 4;
#pragma unroll
    for (int n = 0; n < 4; ++n) {
      uint2 w;
      w.x = (unsigned)f2bf(oacc[g][n][0] * inv) |
            ((unsigned)f2bf(oacc[g][n][1] * inv) << 16);
      w.y = (unsigned)f2bf(oacc[g][n][2] * inv) |
            ((unsigned)f2bf(oacc[g][n][3] * inv) << 16);
      *(uint2*)(cp + n * 16) = w;
    }
  }
}

extern "C" void kernel_launch(void* const* d_in, const int* in_sizes, int n_in,
                              void* d_out, int out_size, void* d_ws, size_t ws_size,
                              hipStream_t stream) {
  const float* q    = (const float*)d_in[0];
  const float* k    = (const float*)d_in[1];
  const float* v    = (const float*)d_in[2];
  const float* mask = (const float*)d_in[3];
  const float* wqkv = (const float*)d_in[4];
  const float* bqkv = (const float*)d_in[5];
  const float* wout = (const float*)d_in[6];
  const float* bout = (const float*)d_in[7];

  char* ws = (char*)d_ws;
  unsigned short* Xb   = (unsigned short*)(ws);
  unsigned short* Wqb  = (unsigned short*)(ws + 50331648);
  unsigned short* Wob  = (unsigned short*)(ws + 56623104);
  unsigned short* QKVb = (unsigned short*)(ws + 58720256);  // [Q|K|Vt] bf16
  unsigned short* CTXb = (unsigned short*)(ws);             // [B][T][E] (Xb dead)

  cvt_kernel<<<2048, 256, 0, stream>>>((const float4*)q, (uint2*)Xb, 2097152);
  cvt_kernel<<<2048, 256, 0, stream>>>((const float4*)k, (uint2*)(Xb + 8388608), 2097152);
  cvt_kernel<<<2048, 256, 0, stream>>>((const float4*)v, (uint2*)(Xb + 16777216), 2097152);
  cvt_kernel<<<1024, 256, 0, stream>>>((const float4*)wqkv, (uint2*)Wqb, 786432);
  cvt_kernel<<<512, 256, 0, stream>>>((const float4*)wout, (uint2*)Wob, 262144);

  gemm_kernel<0><<<dim3(64, 24), 256, 0, stream>>>(Xb, Wqb, bqkv, QKVb, 1024);
  attn_kernel<<<dim3(16, 64), 256, 0, stream>>>(QKVb, QKVb + 8388608,
                                                QKVb + 16777216, mask, CTXb);
  gemm_kernel<1><<<dim3(64, 8), 256, 0, stream>>>(CTXb, Wob, bout, d_out, 1024);
}